// Round 5
// baseline (243.807 us; speedup 1.0000x reference)
//
#include <hip/hip_runtime.h>

#define ROWS 4096
#define NCOL 8192
#define THREADS 512
#define RPB 4                        // rows per block
#define F4PT (NCOL / 4 / THREADS)    // 4 float4 per thread
#define NWAVE (THREADS / 64)         // 8 waves

typedef float nfloat4 __attribute__((ext_vector_type(4)));

// Barrier that fences LDS only: waits lgkmcnt(0) (LDS writes visible) then
// s_barrier — WITHOUT the s_waitcnt vmcnt(0) that __syncthreads emits.
// Keeps prefetch loads + previous row's stores in flight across reductions.
__device__ __forceinline__ void sync_lds() {
    asm volatile("s_waitcnt lgkmcnt(0)\n\ts_barrier" ::: "memory");
}

__global__ __launch_bounds__(THREADS, 4)
void sparsemax_kernel(const float* __restrict__ x, float* __restrict__ out) {
    __shared__ float srow[NCOL];          // 32 KB: current row, thread-private slices
    __shared__ float2 sred[2][NWAVE];     // ping-pong per-wave (sum, count)
    __shared__ float smax[NWAVE];

    const int tid = threadIdx.x;
    const int wave = tid >> 6;
    const int lane = tid & 63;
    float4* sr4 = (float4*)srow;

    const int row0 = blockIdx.x * RPB;

    // Prefetch row 0 into registers.
    float4 pf[F4PT];
    {
        const float4* __restrict__ xr = (const float4*)(x + (size_t)row0 * NCOL);
#pragma unroll
        for (int j = 0; j < F4PT; ++j) pf[j] = xr[tid + THREADS * j];
    }

    for (int r = 0; r < RPB; ++r) {
        // Stage prefetched row into own LDS slice; fused thread-local max.
        float m = -INFINITY;
#pragma unroll
        for (int j = 0; j < F4PT; ++j) {
            float4 q = pf[j];
            sr4[tid + THREADS * j] = q;
            m = fmaxf(m, fmaxf(fmaxf(q.x, q.y), fmaxf(q.z, q.w)));
        }
        // Issue next row's loads NOW; they stay in flight through the tau loop
        // (no __syncthreads anywhere, so no vmcnt(0) drain).
        if (r + 1 < RPB) {
            const float4* __restrict__ xr =
                (const float4*)(x + (size_t)(row0 + r + 1) * NCOL);
#pragma unroll
            for (int j = 0; j < F4PT; ++j) pf[j] = xr[tid + THREADS * j];
        }
        __builtin_amdgcn_sched_barrier(0);  // don't let the loads sink below

        // ---- Block max ----
#pragma unroll
        for (int off = 32; off > 0; off >>= 1)
            m = fmaxf(m, __shfl_down(m, off, 64));
        if (lane == 0) smax[wave] = m;
        sync_lds();
        float mm = smax[0];
#pragma unroll
        for (int w = 1; w < NWAVE; ++w) mm = fmaxf(mm, smax[w]);
        float t = mm - 1.0f;   // candidate threshold; support ⊆ {x > max-1}

        // ---- Michelot fixed-point (exact; stops when support size stable) ----
        float prev_k = -1.0f;
        for (int it = 0; it < 32; ++it) {
            const int b = it & 1;
            float s = 0.0f, kf = 0.0f;
#pragma unroll
            for (int j = 0; j < F4PT; ++j) {
                float4 q = sr4[tid + THREADS * j];
                if (q.x > t) { s += q.x; kf += 1.0f; }
                if (q.y > t) { s += q.y; kf += 1.0f; }
                if (q.z > t) { s += q.z; kf += 1.0f; }
                if (q.w > t) { s += q.w; kf += 1.0f; }
            }
#pragma unroll
            for (int off = 32; off > 0; off >>= 1) {
                s  += __shfl_down(s,  off, 64);
                kf += __shfl_down(kf, off, 64);
            }
            if (lane == 0) sred[b][wave] = make_float2(s, kf);
            sync_lds();
            float st = 0.0f, kt = 0.0f;
#pragma unroll
            for (int w = 0; w < NWAVE; ++w) {
                float2 p = sred[b][w];
                st += p.x; kt += p.y;
            }
            if (kt == prev_k) break;          // uniform across block
            prev_k = kt;
            t = (st - 1.0f) / kt;
        }

        // ---- Epilogue: out = max(x - tau, 0), nontemporal stores ----
        nfloat4* __restrict__ outr = (nfloat4*)(out + (size_t)(row0 + r) * NCOL);
#pragma unroll
        for (int j = 0; j < F4PT; ++j) {
            float4 q = sr4[tid + THREADS * j];
            nfloat4 o;
            o.x = fmaxf(q.x - t, 0.0f);
            o.y = fmaxf(q.y - t, 0.0f);
            o.z = fmaxf(q.z - t, 0.0f);
            o.w = fmaxf(q.w - t, 0.0f);
            __builtin_nontemporal_store(o, &outr[tid + THREADS * j]);
        }
        // Next iteration's ds_write of pf waits only on the pf loads (precise
        // vmcnt), not on these stores — they keep draining under compute.
    }
}

extern "C" void kernel_launch(void* const* d_in, const int* in_sizes, int n_in,
                              void* d_out, int out_size, void* d_ws, size_t ws_size,
                              hipStream_t stream) {
    const float* x = (const float*)d_in[0];
    float* out = (float*)d_out;
    sparsemax_kernel<<<ROWS / RPB, THREADS, 0, stream>>>(x, out);
}